// Round 16
// baseline (122.741 us; speedup 1.0000x reference)
//
#include <hip/hip_runtime.h>

// VQ quantize: z [16,256,64,64] f32, weight [1024,256] f32.
// Outputs (f32, concat): quantized, straight_through (== quantized numerically), indices.
//
// prep: z -> fp16 tiled [o][n][8] (float4-vectorized); w -> fp16 (x1024, exact pow2)
//       tiled [o][c][8]; wn = np-replicated fp32 ||w||^2.
// argmin: one fp16 MFMA pass, BM=256 x BN=128 per block (higher arithmetic intensity:
//         32 MFMA per staged 24KB step), 4 waves x (128 rows x 64 codes), BK=32 x 8
//         steps, 2x24KB dbuf + counted vmcnt(6) pipeline, bijective XCD remap;
//         value-only DPP min epilogue; per (row, 64-code entry): top-1 value + W-mask.
// finrescue: merge 16 entries by (value, entry) (= np first-index ties), flag
//         margin<TAU or popcount>1; flagged rows get bit-exact numpy rescore of ONLY
//         candidate codes (validated r3-r15).
// gather: codebook rows into both outputs.

#define NROWS 65536
#define DDIM 256
#define KCODES 1024
#define TAU 2e-4f
#define WWIN 2e-4f

typedef unsigned long long u64;
typedef _Float16 f16x8 __attribute__((ext_vector_type(8)));
typedef float f32x4 __attribute__((ext_vector_type(4)));

__device__ __forceinline__ void gld16(const void* g, void* l) {
    __builtin_amdgcn_global_load_lds((const __attribute__((address_space(1))) void*)g,
                                     (__attribute__((address_space(3))) void*)l, 16, 0, 0);
}

// numpy pairwise fp32 sum of 256 fl(x_i^2): 128+128 split, 8 accumulators per half,
// fixed combine tree. Bit-matches np.sum(flat*flat, axis=1) (validated r3..r15).
template <typename F>
__device__ __forceinline__ float np_pairwise256_sq(F get) {
    float half[2];
#pragma unroll
    for (int h = 0; h < 2; ++h) {
        float r[8];
#pragma unroll
        for (int j = 0; j < 8; ++j) { float v = get(h * 128 + j); r[j] = __fmul_rn(v, v); }
        for (int i = 8; i < 128; i += 8)
#pragma unroll
            for (int j = 0; j < 8; ++j) {
                float v = get(h * 128 + i + j);
                r[j] = __fadd_rn(r[j], __fmul_rn(v, v));
            }
        half[h] = __fadd_rn(__fadd_rn(__fadd_rn(r[0], r[1]), __fadd_rn(r[2], r[3])),
                            __fadd_rn(__fadd_rn(r[4], r[5]), __fadd_rn(r[6], r[7])));
    }
    return __fadd_rn(half[0], half[1]);
}

// ---------------- fused prep: zprep (0..2047) | wprep (..2175) | wnorm (..2179) ----
__global__ void prep_k(const float* __restrict__ z, const float* __restrict__ w,
                       f16x8* __restrict__ z16, f16x8* __restrict__ w16,
                       float* __restrict__ wn) {
    int bid = blockIdx.x;
    if (bid < 2048) {
        int tid = bid * 256 + threadIdx.x;       // 512K threads
        int n4 = tid & 16383;                    // n-quad index
        int o  = tid >> 14;                      // 0..31
        int n  = n4 * 4;
        const float* zp = z + (size_t)(n >> 12) * 1048576 + (n & 4095);
        f16x8 h0, h1, h2, h3;
#pragma unroll
        for (int j = 0; j < 8; ++j) {
            float4 v = *reinterpret_cast<const float4*>(zp + (size_t)(o * 8 + j) * 4096);
            h0[j] = (_Float16)v.x;
            h1[j] = (_Float16)v.y;
            h2[j] = (_Float16)v.z;
            h3[j] = (_Float16)v.w;
        }
        f16x8* zo = z16 + (size_t)o * 65536 + n;
        zo[0] = h0; zo[1] = h1; zo[2] = h2; zo[3] = h3;
    } else if (bid < 2176) {
        int idx = (bid - 2048) * 256 + threadIdx.x;   // 32768 items
        int o = idx >> 10, c = idx & 1023;
        const float* wp = w + (size_t)c * DDIM + o * 8;
        f16x8 hv;
#pragma unroll
        for (int j = 0; j < 8; ++j) hv[j] = (_Float16)(wp[j] * 1024.0f);  // pow2: exact
        w16[(size_t)o * 1024 + c] = hv;
    } else {
        int k = (bid - 2176) * 256 + threadIdx.x;
        const float* wp = w + (size_t)k * DDIM;
        wn[k] = np_pairwise256_sq([&](int i) { return wp[i]; });
    }
}

// DPP min stage (16-lane group): pure VALU.
#define DPP_MIN(CTRL) {                                                                 \
    float ov = __int_as_float(__builtin_amdgcn_mov_dpp(__float_as_int(bv), CTRL, 0xf, 0xf, false)); \
    bv = fminf(bv, ov); }

// ---------------- fp16-MFMA distance; BM=256 high-intensity tile ----------------
// Block: 256 rows x 128 codes; 4 waves 2x2 (wm row-half of 128, wn_ code-half of 64).
// XCD remap (bijective): p=(lo3,mid3,hi5) -> cb=mid3, rowgroup g=(lo3<<5)|hi5.
// Pipeline (r14-proven): STAGE(s+1) -> vmcnt(6) -> barrier -> COMPUTE(s) -> barrier.
__launch_bounds__(256, 2)
__global__ void argmin_mfma_k(const f16x8* __restrict__ z16, const f16x8* __restrict__ w16,
                              const float* __restrict__ wn,
                              float* __restrict__ btv, u64* __restrict__ bmk) {
    __shared__ char arena[49152];               // 2 x (A 16KB | B 8KB)
    const int t = threadIdx.x;
    const int lane = t & 63;
    const int l15 = lane & 15, l4 = lane >> 4;
    const int wid = t >> 6;                     // 0..3
    const int wm = wid >> 1, wn_ = wid & 1;
    const int p = blockIdx.x;
    const int cb = (p >> 3) & 7;
    const int n0 = ((((p & 7) << 5) | (p >> 6)) << 8);   // rowgroup * 256
    const int c0 = cb << 7;

    f32x4 acc[8][4];
#pragma unroll
    for (int mt = 0; mt < 8; ++mt)
#pragma unroll
        for (int nt = 0; nt < 4; ++nt) acc[mt][nt] = f32x4{0.f, 0.f, 0.f, 0.f};

    // STAGE(s,buf): A 16KB (4 octets x 256 rows) + B 8KB (4 octets x 128 codes).
    // Wave wid: 4 A-chunks (ia=wid*4+qa) + 2 B-chunks (ib=wid*2+qb), 1KB each.
    auto STAGE = [&](int s, int buf) {
        char* lA = arena + buf * 24576;
        char* lB = lA + 16384;
#pragma unroll
        for (int qa = 0; qa < 4; ++qa) {
            int ia = wid * 4 + qa;              // 0..15
            int o = s * 4 + (ia >> 2);
            int rq = ia & 3;                    // row-quarter (64 rows)
            gld16(z16 + (size_t)(o * 65536 + n0 + rq * 64 + lane), lA + ia * 1024);
        }
#pragma unroll
        for (int qb = 0; qb < 2; ++qb) {
            int ib = wid * 2 + qb;              // 0..7
            int o = s * 4 + (ib >> 1);
            int half = ib & 1;
            gld16(w16 + (size_t)(o * 1024 + c0 + half * 64 + lane), lB + ib * 1024);
        }
    };
    auto COMPUTE = [&](int buf) {
        char* lA = arena + buf * 24576;
        char* lB = lA + 16384;
        f16x8 b[4];
        const char* pb = lB + l4 * 2048 + (wn_ * 64 + l15) * 16;
#pragma unroll
        for (int nt = 0; nt < 4; ++nt) b[nt] = *reinterpret_cast<const f16x8*>(pb + nt * 256);
        const char* pa = lA + l4 * 4096 + (wm * 128 + l15) * 16;
#pragma unroll
        for (int mt = 0; mt < 8; ++mt) {
            f16x8 a = *reinterpret_cast<const f16x8*>(pa + mt * 256);
#pragma unroll
            for (int nt = 0; nt < 4; ++nt)
                acc[mt][nt] = __builtin_amdgcn_mfma_f32_16x16x32_f16(a, b[nt], acc[mt][nt], 0, 0, 0);
        }
    };

    STAGE(0, 0);
#pragma unroll
    for (int s = 0; s < 7; ++s) {
        STAGE(s + 1, (s + 1) & 1);
        asm volatile("s_waitcnt vmcnt(6)" ::: "memory");   // step-s loads landed; s+1 in flight
        __builtin_amdgcn_s_barrier();
        COMPUTE(s & 1);
        __builtin_amdgcn_s_barrier();                      // reads done before overwrite
    }
    asm volatile("s_waitcnt vmcnt(0)" ::: "memory");
    __builtin_amdgcn_s_barrier();
    COMPUTE(1);

    // ---- epilogue: s = wn - 2^-9 m'; per (row, entry e=cb*2+wn_): top1 + W-mask ----
    float wnv[4];
#pragma unroll
    for (int nt = 0; nt < 4; ++nt) wnv[nt] = wn[c0 + wn_ * 64 + nt * 16 + l15];
    const int ebase = ((cb << 1) | wn_) << 16;

#pragma unroll
    for (int mt = 0; mt < 8; ++mt) {
#pragma unroll
        for (int r = 0; r < 4; ++r) {
            // C/D layout: col = lane&15, row = (lane>>4)*4 + r
            float s0 = fmaf(-0.001953125f, acc[mt][0][r], wnv[0]);   // -2^-9 (w x1024)
            float s1 = fmaf(-0.001953125f, acc[mt][1][r], wnv[1]);
            float s2 = fmaf(-0.001953125f, acc[mt][2][r], wnv[2]);
            float s3 = fmaf(-0.001953125f, acc[mt][3][r], wnv[3]);
            float bv = fminf(fminf(s0, s1), fminf(s2, s3));
            DPP_MIN(0xB1)      // quad_perm [1,0,3,2]
            DPP_MIN(0x4E)      // quad_perm [2,3,0,1]
            DPP_MIN(0x141)     // row_half_mirror
            DPP_MIN(0x140)     // row_mirror  -> bv = 16-lane-group min
            float thr = bv + WWIN;
            u64 b0 = __ballot(s0 < thr), b1 = __ballot(s1 < thr);
            u64 b2 = __ballot(s2 < thr), b3 = __ballot(s3 < thr);
            int sh = 16 * l4;
            u64 msk = ((b0 >> sh) & 0xFFFFull)
                    | (((b1 >> sh) & 0xFFFFull) << 16)
                    | (((b2 >> sh) & 0xFFFFull) << 32)
                    | (((b3 >> sh) & 0xFFFFull) << 48);
            if (l15 == 0) {
                int row = wm * 128 + mt * 16 + l4 * 4 + r;
                btv[ebase + n0 + row] = bv;
                bmk[ebase + n0 + row] = msk;
            }
        }
    }
}

// ---------------- finalize+rescue fused: per 16-row group, 64 threads ----------------
__global__ void finrescue_k(const float* __restrict__ z, const float* __restrict__ w,
                            const float* __restrict__ s2,
                            const float* __restrict__ btv, const u64* __restrict__ bmk,
                            float* __restrict__ idxf_out) {
    __shared__ float zsh[16][256];              // 16KB panel
    const int lane = threadIdx.x;               // 0..63
    const int n0 = blockIdx.x * 16;
    const int r = lane >> 2;                    // row 0..15
    const int eq = lane & 3;                    // entry quarter
    const int n = n0 + r;

    // merge 16 entry-top1s by (value, entry) — entry order == code-block order,
    // so (v,e) ordering reproduces np first-index tie semantics across entries.
    float bv = 3.4e38f, b2 = 3.4e38f;
    int be = 0;
#pragma unroll
    for (int i = 0; i < 4; ++i) {
        int e = eq * 4 + i;
        float v = btv[(e << 16) + n];
        if (v < bv) { b2 = bv; bv = v; be = e; }    // e ascending: strict < keeps first
        else b2 = fminf(b2, v);
    }
#pragma unroll
    for (int m = 1; m < 4; m <<= 1) {
        float ov = __shfl_xor(bv, m), o2 = __shfl_xor(b2, m);
        int oe = __shfl_xor(be, m);
        if (ov < bv || (ov == bv && oe < be)) { b2 = fminf(bv, o2); bv = ov; be = oe; }
        else b2 = fminf(b2, ov);
    }
    u64 wmask = bmk[((u64)be << 16) + n];
    // index = first bit of winning entry's window mask (exact when popcount==1;
    // popcount>1 => flagged => rescue recomputes bit-exactly below)
    int bi = be * 64 + (int)(__ffsll((long long)wmask) - 1);
    bool flag = (__popcll(wmask) > 1) || (b2 - bv < TAU);
    if (eq == 0) idxf_out[n] = (float)bi;
    u64 fb = __ballot(flag);
    if ((fb & 0x1111111111111111ull) == 0) return;

    // cooperative z panel (rows share 64B lines)
    const float* zb = z + (size_t)(n0 >> 12) * 1048576 + (n0 & 4095);
#pragma unroll
    for (int it = 0; it < 16; ++it) {
        int d = it * 16 + (lane >> 2);
        float4 v = *reinterpret_cast<const float4*>(zb + (size_t)d * 4096 + (lane & 3) * 4);
        zsh[(lane & 3) * 4 + 0][d] = v.x;
        zsh[(lane & 3) * 4 + 1][d] = v.y;
        zsh[(lane & 3) * 4 + 2][d] = v.z;
        zsh[(lane & 3) * 4 + 3][d] = v.w;
    }
    __syncthreads();

    for (int r2 = 0; r2 < 16; ++r2) {
        if (!((fb >> (r2 * 4)) & 1)) continue;
        int nn = n0 + r2;
        // s1: numpy pairwise tree, wave-parallel exact (lanes (h,j) own accumulators)
        int hh = (lane >> 3) & 1, jj = lane & 7;
        float v0 = zsh[r2][hh * 128 + jj];
        float accj = __fmul_rn(v0, v0);
#pragma unroll
        for (int i = 1; i < 16; ++i) {
            float v2 = zsh[r2][hh * 128 + i * 8 + jj];
            accj = __fadd_rn(accj, __fmul_rn(v2, v2));
        }
        float a1 = __fadd_rn(accj, __shfl_xor(accj, 1));
        float a2 = __fadd_rn(a1, __shfl_xor(a1, 2));
        float a4 = __fadd_rn(a2, __shfl_xor(a2, 4));
        float s1 = __fadd_rn(a4, __shfl_xor(a4, 8));

        float gv = __shfl(bv, r2 * 4);          // global min of row r2 (from merge phase)

        float zr0 = zsh[r2][lane * 4 + 0], zr1 = zsh[r2][lane * 4 + 1];
        float zr2 = zsh[r2][lane * 4 + 2], zr3 = zsh[r2][lane * 4 + 3];
        float bv2 = 3.4e38f;
        int   bi2 = 0;
        for (int e = 0; e < 16; ++e) {          // ascending codes -> first-index ties
            float tv = btv[(e << 16) + nn];
            if (tv <= gv + TAU) {
                u64 m = bmk[((u64)e << 16) + nn];
                while (m) {
                    int k = __ffsll((long long)m) - 1;
                    m &= m - 1;
                    int c = e * 64 + k;
                    const float* wp = w + (size_t)c * DDIM + lane * 4;
                    double md = 0.0;
                    md = fma((double)zr0, (double)wp[0], md);
                    md = fma((double)zr1, (double)wp[1], md);
                    md = fma((double)zr2, (double)wp[2], md);
                    md = fma((double)zr3, (double)wp[3], md);
#pragma unroll
                    for (int mm = 1; mm < 64; mm <<= 1) md += __shfl_xor(md, mm);
                    float dq = __fadd_rn((float)((double)s1 - 2.0 * md), s2[c]);
                    if (dq < bv2) { bv2 = dq; bi2 = c; }
                }
            }
        }
        if (lane == 0) idxf_out[nn] = (float)bi2;
    }
}

// ---------------- gather quantized = weight[idx] into [b,c,h,w] x2 ----------------
__global__ void gather_k(const float* __restrict__ idxf, const float* __restrict__ w,
                         float* __restrict__ out0, float* __restrict__ out1) {
    int tid = blockIdx.x * 256 + threadIdx.x;
    int n   = tid & 65535;
    int c4  = tid >> 16;
    int code = (int)idxf[n];
    float4 v = *reinterpret_cast<const float4*>(w + (size_t)code * DDIM + c4 * 4);
    size_t off = (size_t)(n >> 12) * 1048576 + (size_t)c4 * 4 * 4096 + (n & 4095);
    out0[off]         = v.x;
    out0[off + 4096]  = v.y;
    out0[off + 8192]  = v.z;
    out0[off + 12288] = v.w;
    out1[off]         = v.x;
    out1[off + 4096]  = v.y;
    out1[off + 8192]  = v.z;
    out1[off + 12288] = v.w;
}

extern "C" void kernel_launch(void* const* d_in, const int* in_sizes, int n_in,
                              void* d_out, int out_size, void* d_ws, size_t ws_size,
                              hipStream_t stream) {
    const float* z = (const float*)d_in[0];
    const float* w = (const float*)d_in[1];
    float* out    = (float*)d_out;
    float* out0   = out;
    float* out1   = out + 16777216;
    float* outidx = out + 33554432;

    // scratch inside d_out (consumed before gather_k overwrites):
    f16x8* z16 = (f16x8*)out0;                              // 32MB in out0 (64MB region)
    char* s1b = (char*)out1;
    f16x8* w16 = (f16x8*)s1b;                               // 512KB
    float* wn  = (float*)(s1b + 1048576);                   // 4KB
    float* btv = (float*)(s1b + 2097152);                   // 4MB  [16][65536]
    u64*   bmk = (u64*)(s1b + 10485760);                    // 8MB  [16][65536]

    prep_k<<<2180, 256, 0, stream>>>(z, w, z16, w16, wn);
    argmin_mfma_k<<<(NROWS / 256) * 8, 256, 0, stream>>>(z16, w16, wn, btv, bmk);
    finrescue_k<<<NROWS / 16, 64, 0, stream>>>(z, w, wn, btv, bmk, outidx);
    gather_k<<<NROWS * 64 / 256, 256, 0, stream>>>(outidx, w, out0, out1);
}

// Round 17
// 116.360 us; speedup vs baseline: 1.0548x; 1.0548x over previous
//
#include <hip/hip_runtime.h>

// VQ quantize: z [16,256,64,64] f32, weight [1024,256] f32.
// Outputs (f32, concat): quantized, straight_through (== quantized numerically), indices.
//
// prep: zprep via LDS-TILED TRANSPOSE (contiguous 2KB global reads -> f16 LDS tile ->
//       coalesced tiled stores) — the old direct transpose-read pattern was strided
//       (256B @ 16KB stride) and HBM-inefficient. w -> fp16 (x1024) tiled; wn = np ||w||^2.
// argmin (r14, frozen): fp16 MFMA, gld16 LDS staging, counted vmcnt(4) dbuf pipeline,
//       BK=32 x 8 steps, XCD-grouped blocks, value-only DPP min epilogue; per (row,
//       64-code entry): top-1 value + W-window mask.
// finrescue (frozen): merge 16 entries by (value, entry); flag margin<TAU or popcount>1;
//       flagged rows -> bit-exact numpy rescore of candidate codes (validated r3-r16).
// gather (frozen): codebook rows into both outputs.

#define NROWS 65536
#define DDIM 256
#define KCODES 1024
#define TAU 2e-4f
#define WWIN 2e-4f

typedef unsigned long long u64;
typedef _Float16 f16x8 __attribute__((ext_vector_type(8)));
typedef float f32x4 __attribute__((ext_vector_type(4)));

__device__ __forceinline__ void gld16(const void* g, void* l) {
    __builtin_amdgcn_global_load_lds((const __attribute__((address_space(1))) void*)g,
                                     (__attribute__((address_space(3))) void*)l, 16, 0, 0);
}
__device__ __forceinline__ unsigned short f2h(float x) {
    union { _Float16 h; unsigned short u; } cv;
    cv.h = (_Float16)x;                      // v_cvt_f16_f32, RNE (same as all prior rounds)
    return cv.u;
}

// numpy pairwise fp32 sum of 256 fl(x_i^2): 128+128 split, 8 accumulators per half,
// fixed combine tree. Bit-matches np.sum(flat*flat, axis=1) (validated r3..r16).
template <typename F>
__device__ __forceinline__ float np_pairwise256_sq(F get) {
    float half[2];
#pragma unroll
    for (int h = 0; h < 2; ++h) {
        float r[8];
#pragma unroll
        for (int j = 0; j < 8; ++j) { float v = get(h * 128 + j); r[j] = __fmul_rn(v, v); }
        for (int i = 8; i < 128; i += 8)
#pragma unroll
            for (int j = 0; j < 8; ++j) {
                float v = get(h * 128 + i + j);
                r[j] = __fadd_rn(r[j], __fmul_rn(v, v));
            }
        half[h] = __fadd_rn(__fadd_rn(__fadd_rn(r[0], r[1]), __fadd_rn(r[2], r[3])),
                            __fadd_rn(__fadd_rn(r[4], r[5]), __fadd_rn(r[6], r[7])));
    }
    return __fadd_rn(half[0], half[1]);
}

// ---------------- fused prep ----------------
// zprep blocks [0,1024): tile = 8 d-lines x 2048 n. Reads CONTIGUOUS (2KB runs),
// transpose via 32KB LDS, stores coalesced 1KB. wprep [1024,1152), wnorm [1152,1156).
__global__ __launch_bounds__(256) void prep_k(const float* __restrict__ z,
                                              const float* __restrict__ w,
                                              f16x8* __restrict__ z16,
                                              f16x8* __restrict__ w16,
                                              float* __restrict__ wn) {
    __shared__ char lds[32768];                  // [8 d][2048 n] f16
    int bid = blockIdx.x;
    int t = threadIdx.x;
    if (bid < 1024) {
        int o   = bid >> 5;                      // 0..31 (d-octet)
        int seg = bid & 31;                      // (b, n-half)
        int b   = seg >> 1, nh = seg & 1;
        const float* zbase = z + (size_t)b * 1048576 + (size_t)(o * 8) * 4096 + nh * 2048;
        // load 8 x 2048 f32 (contiguous per line), convert, write LDS [dl][n]
#pragma unroll
        for (int i = 0; i < 16; ++i) {
            int q  = i * 256 + t;                // quad index 0..4095
            int dl = q >> 9;                     // 0..7
            int nq = q & 511;                    // n-quad within 2048
            float4 v = *reinterpret_cast<const float4*>(zbase + (size_t)dl * 4096 + nq * 4);
            short4 s = {(short)f2h(v.x), (short)f2h(v.y), (short)f2h(v.z), (short)f2h(v.w)};
            *reinterpret_cast<short4*>(lds + dl * 4096 + nq * 8) = s;
        }
        __syncthreads();
        // emit records z16[o][n][8]: 8 x u16 LDS column reads (128B contiguous/wave)
        int ngbase = b * 4096 + nh * 2048;
#pragma unroll
        for (int r = 0; r < 8; ++r) {
            int nl = r * 256 + t;                // 0..2047
            short8v: ;
            union { f16x8 h; short s[8]; } rec;
#pragma unroll
            for (int j = 0; j < 8; ++j)
                rec.s[j] = *reinterpret_cast<const short*>(lds + j * 4096 + nl * 2);
            z16[(size_t)o * 65536 + ngbase + nl] = rec.h;
        }
    } else if (bid < 1152) {
        int idx = (bid - 1024) * 256 + t;        // 32768 items
        int o = idx >> 10, c = idx & 1023;
        const float* wp = w + (size_t)c * DDIM + o * 8;
        f16x8 hv;
#pragma unroll
        for (int j = 0; j < 8; ++j) hv[j] = (_Float16)(wp[j] * 1024.0f);  // pow2: exact
        w16[(size_t)o * 1024 + c] = hv;
    } else {
        int k = (bid - 1152) * 256 + t;
        const float* wp = w + (size_t)k * DDIM;
        wn[k] = np_pairwise256_sq([&](int i) { return wp[i]; });
    }
}

// DPP min stage (16-lane group): pure VALU.
#define DPP_MIN(CTRL) {                                                                 \
    float ov = __int_as_float(__builtin_amdgcn_mov_dpp(__float_as_int(bv), CTRL, 0xf, 0xf, false)); \
    bv = fminf(bv, ov); }

// ---------------- fp16-MFMA distance; counted-vmcnt LDS pipeline (r14, frozen) -----
__launch_bounds__(256, 4)
__global__ void argmin_mfma_k(const f16x8* __restrict__ z16, const f16x8* __restrict__ w16,
                              const float* __restrict__ wn,
                              float* __restrict__ btv, u64* __restrict__ bmk) {
    __shared__ char arena[32768];               // 2 x (A 8KB | B 8KB)
    const int t = threadIdx.x;
    const int lane = t & 63;
    const int l15 = lane & 15, l4 = lane >> 4;
    const int wid = t >> 6;                     // 0..3
    const int wm = wid >> 1, wn_ = wid & 1;
    const int p = blockIdx.x;
    const int cb = (p >> 3) & 7;                // remap: same-n0 group shares XCD
    const int n0 = ((((p & 7) << 6) | (p >> 6)) << 7);
    const int c0 = cb << 7;

    f32x4 acc[4][4];
#pragma unroll
    for (int mt = 0; mt < 4; ++mt)
#pragma unroll
        for (int nt = 0; nt < 4; ++nt) acc[mt][nt] = f32x4{0.f, 0.f, 0.f, 0.f};

    auto STAGE = [&](int s, int buf) {
        char* lA = arena + buf * 16384;
        char* lB = lA + 8192;
#pragma unroll
        for (int q = 0; q < 2; ++q) {
            int i = wid * 2 + q;                // chunk 0..7
            int o = s * 4 + (i >> 1);
            int half = i & 1;
            gld16(z16 + (size_t)(o * 65536 + n0 + half * 64 + lane), lA + i * 1024);
            gld16(w16 + (size_t)(o * 1024 + c0 + half * 64 + lane), lB + i * 1024);
        }
    };
    auto COMPUTE = [&](int buf) {
        char* lA = arena + buf * 16384;
        char* lB = lA + 8192;
        f16x8 a[4], b[4];
        const char* pa = lA + l4 * 2048 + (wm * 64 + l15) * 16;
#pragma unroll
        for (int mt = 0; mt < 4; ++mt) a[mt] = *reinterpret_cast<const f16x8*>(pa + mt * 256);
        const char* pb = lB + l4 * 2048 + (wn_ * 64 + l15) * 16;
#pragma unroll
        for (int nt = 0; nt < 4; ++nt) b[nt] = *reinterpret_cast<const f16x8*>(pb + nt * 256);
#pragma unroll
        for (int mt = 0; mt < 4; ++mt)
#pragma unroll
            for (int nt = 0; nt < 4; ++nt)
                acc[mt][nt] = __builtin_amdgcn_mfma_f32_16x16x32_f16(a[mt], b[nt], acc[mt][nt], 0, 0, 0);
    };

    STAGE(0, 0);
#pragma unroll
    for (int s = 0; s < 7; ++s) {
        STAGE(s + 1, (s + 1) & 1);
        asm volatile("s_waitcnt vmcnt(4)" ::: "memory");   // step-s loads landed; s+1 in flight
        __builtin_amdgcn_s_barrier();
        COMPUTE(s & 1);
        __builtin_amdgcn_s_barrier();                      // reads done before overwrite
    }
    asm volatile("s_waitcnt vmcnt(0)" ::: "memory");
    __builtin_amdgcn_s_barrier();
    COMPUTE(1);

    // ---- epilogue: s = wn - 2^-9 m'; per (row, entry e=cb*2+wn_): top1 + W-mask ----
    float wnv[4];
#pragma unroll
    for (int nt = 0; nt < 4; ++nt) wnv[nt] = wn[c0 + wn_ * 64 + nt * 16 + l15];
    const int ebase = ((cb << 1) | wn_) << 16;

#pragma unroll
    for (int mt = 0; mt < 4; ++mt) {
#pragma unroll
        for (int r = 0; r < 4; ++r) {
            // C/D layout: col = lane&15, row = (lane>>4)*4 + r
            float s0 = fmaf(-0.001953125f, acc[mt][0][r], wnv[0]);   // -2^-9 (w x1024)
            float s1 = fmaf(-0.001953125f, acc[mt][1][r], wnv[1]);
            float s2 = fmaf(-0.001953125f, acc[mt][2][r], wnv[2]);
            float s3 = fmaf(-0.001953125f, acc[mt][3][r], wnv[3]);
            float bv = fminf(fminf(s0, s1), fminf(s2, s3));
            DPP_MIN(0xB1)      // quad_perm [1,0,3,2]
            DPP_MIN(0x4E)      // quad_perm [2,3,0,1]
            DPP_MIN(0x141)     // row_half_mirror
            DPP_MIN(0x140)     // row_mirror  -> bv = 16-lane-group min
            float thr = bv + WWIN;
            u64 b0 = __ballot(s0 < thr), b1 = __ballot(s1 < thr);
            u64 b2 = __ballot(s2 < thr), b3 = __ballot(s3 < thr);
            int sh = 16 * l4;
            u64 msk = ((b0 >> sh) & 0xFFFFull)
                    | (((b1 >> sh) & 0xFFFFull) << 16)
                    | (((b2 >> sh) & 0xFFFFull) << 32)
                    | (((b3 >> sh) & 0xFFFFull) << 48);
            if (l15 == 0) {
                int row = wm * 64 + mt * 16 + l4 * 4 + r;
                btv[ebase + n0 + row] = bv;
                bmk[ebase + n0 + row] = msk;
            }
        }
    }
}

// ---------------- finalize+rescue fused (frozen): per 16-row group, 64 threads ------
__global__ void finrescue_k(const float* __restrict__ z, const float* __restrict__ w,
                            const float* __restrict__ s2,
                            const float* __restrict__ btv, const u64* __restrict__ bmk,
                            float* __restrict__ idxf_out) {
    __shared__ float zsh[16][256];              // 16KB panel
    const int lane = threadIdx.x;               // 0..63
    const int n0 = blockIdx.x * 16;
    const int r = lane >> 2;                    // row 0..15
    const int eq = lane & 3;                    // entry quarter
    const int n = n0 + r;

    float bv = 3.4e38f, b2 = 3.4e38f;
    int be = 0;
#pragma unroll
    for (int i = 0; i < 4; ++i) {
        int e = eq * 4 + i;
        float v = btv[(e << 16) + n];
        if (v < bv) { b2 = bv; bv = v; be = e; }    // e ascending: strict < keeps first
        else b2 = fminf(b2, v);
    }
#pragma unroll
    for (int m = 1; m < 4; m <<= 1) {
        float ov = __shfl_xor(bv, m), o2 = __shfl_xor(b2, m);
        int oe = __shfl_xor(be, m);
        if (ov < bv || (ov == bv && oe < be)) { b2 = fminf(bv, o2); bv = ov; be = oe; }
        else b2 = fminf(b2, ov);
    }
    u64 wmask = bmk[((u64)be << 16) + n];
    int bi = be * 64 + (int)(__ffsll((long long)wmask) - 1);
    bool flag = (__popcll(wmask) > 1) || (b2 - bv < TAU);
    if (eq == 0) idxf_out[n] = (float)bi;
    u64 fb = __ballot(flag);
    if ((fb & 0x1111111111111111ull) == 0) return;

    const float* zb = z + (size_t)(n0 >> 12) * 1048576 + (n0 & 4095);
#pragma unroll
    for (int it = 0; it < 16; ++it) {
        int d = it * 16 + (lane >> 2);
        float4 v = *reinterpret_cast<const float4*>(zb + (size_t)d * 4096 + (lane & 3) * 4);
        zsh[(lane & 3) * 4 + 0][d] = v.x;
        zsh[(lane & 3) * 4 + 1][d] = v.y;
        zsh[(lane & 3) * 4 + 2][d] = v.z;
        zsh[(lane & 3) * 4 + 3][d] = v.w;
    }
    __syncthreads();

    for (int r2 = 0; r2 < 16; ++r2) {
        if (!((fb >> (r2 * 4)) & 1)) continue;
        int nn = n0 + r2;
        int hh = (lane >> 3) & 1, jj = lane & 7;
        float v0 = zsh[r2][hh * 128 + jj];
        float accj = __fmul_rn(v0, v0);
#pragma unroll
        for (int i = 1; i < 16; ++i) {
            float v2 = zsh[r2][hh * 128 + i * 8 + jj];
            accj = __fadd_rn(accj, __fmul_rn(v2, v2));
        }
        float a1 = __fadd_rn(accj, __shfl_xor(accj, 1));
        float a2 = __fadd_rn(a1, __shfl_xor(a1, 2));
        float a4 = __fadd_rn(a2, __shfl_xor(a2, 4));
        float s1 = __fadd_rn(a4, __shfl_xor(a4, 8));

        float gv = __shfl(bv, r2 * 4);          // global min of row r2 (from merge phase)

        float zr0 = zsh[r2][lane * 4 + 0], zr1 = zsh[r2][lane * 4 + 1];
        float zr2 = zsh[r2][lane * 4 + 2], zr3 = zsh[r2][lane * 4 + 3];
        float bv2 = 3.4e38f;
        int   bi2 = 0;
        for (int e = 0; e < 16; ++e) {          // ascending codes -> first-index ties
            float tv = btv[(e << 16) + nn];
            if (tv <= gv + TAU) {
                u64 m = bmk[((u64)e << 16) + nn];
                while (m) {
                    int k = __ffsll((long long)m) - 1;
                    m &= m - 1;
                    int c = e * 64 + k;
                    const float* wp = w + (size_t)c * DDIM + lane * 4;
                    double md = 0.0;
                    md = fma((double)zr0, (double)wp[0], md);
                    md = fma((double)zr1, (double)wp[1], md);
                    md = fma((double)zr2, (double)wp[2], md);
                    md = fma((double)zr3, (double)wp[3], md);
#pragma unroll
                    for (int mm = 1; mm < 64; mm <<= 1) md += __shfl_xor(md, mm);
                    float dq = __fadd_rn((float)((double)s1 - 2.0 * md), s2[c]);
                    if (dq < bv2) { bv2 = dq; bi2 = c; }
                }
            }
        }
        if (lane == 0) idxf_out[nn] = (float)bi2;
    }
}

// ---------------- gather quantized = weight[idx] into [b,c,h,w] x2 (frozen) --------
__global__ void gather_k(const float* __restrict__ idxf, const float* __restrict__ w,
                         float* __restrict__ out0, float* __restrict__ out1) {
    int tid = blockIdx.x * 256 + threadIdx.x;
    int n   = tid & 65535;
    int c4  = tid >> 16;
    int code = (int)idxf[n];
    float4 v = *reinterpret_cast<const float4*>(w + (size_t)code * DDIM + c4 * 4);
    size_t off = (size_t)(n >> 12) * 1048576 + (size_t)c4 * 4 * 4096 + (n & 4095);
    out0[off]         = v.x;
    out0[off + 4096]  = v.y;
    out0[off + 8192]  = v.z;
    out0[off + 12288] = v.w;
    out1[off]         = v.x;
    out1[off + 4096]  = v.y;
    out1[off + 8192]  = v.z;
    out1[off + 12288] = v.w;
}

extern "C" void kernel_launch(void* const* d_in, const int* in_sizes, int n_in,
                              void* d_out, int out_size, void* d_ws, size_t ws_size,
                              hipStream_t stream) {
    const float* z = (const float*)d_in[0];
    const float* w = (const float*)d_in[1];
    float* out    = (float*)d_out;
    float* out0   = out;
    float* out1   = out + 16777216;
    float* outidx = out + 33554432;

    // scratch inside d_out (consumed before gather_k overwrites):
    f16x8* z16 = (f16x8*)out0;                              // 32MB in out0 (64MB region)
    char* s1b = (char*)out1;
    f16x8* w16 = (f16x8*)s1b;                               // 512KB
    float* wn  = (float*)(s1b + 1048576);                   // 4KB
    float* btv = (float*)(s1b + 2097152);                   // 4MB  [16][65536]
    u64*   bmk = (u64*)(s1b + 10485760);                    // 8MB  [16][65536]

    prep_k<<<1156, 256, 0, stream>>>(z, w, z16, w16, wn);
    argmin_mfma_k<<<(NROWS / 128) * 8, 256, 0, stream>>>(z16, w16, wn, btv, bmk);
    finrescue_k<<<NROWS / 16, 64, 0, stream>>>(z, w, wn, btv, bmk, outidx);
    gather_k<<<NROWS * 64 / 256, 256, 0, stream>>>(outidx, w, out0, out1);
}

// Round 19
// 111.477 us; speedup vs baseline: 1.1010x; 1.0438x over previous
//
#include <hip/hip_runtime.h>

// VQ quantize: z [16,256,64,64] f32, weight [1024,256] f32.
// Outputs (f32, concat): quantized, straight_through (== quantized numerically), indices.
//
// prep_w: w -> fp16 (x1024, exact pow2) tiled [o][c][8]; wn = np-replicated ||w||^2.
// argmin_fused: block = 128 rows x ALL 1024 codes.
//   Phase A (once/block): fp32 z -> f16 A-LDS [o][aswz(row)][8] via coalesced dwordx4
//   loads + in-register 4x8 transpose + XOR-swizzled ds_write (r12-validated pair).
//   Phase B: 8 code-blocks x 8 K-steps; B-only gld16 staging (2/wave/step), 2x8KB dbuf,
//   counted vmcnt(2) pipeline. Cross-cb prefetch goes to buf0 (last read at s=6, sealed
//   by its trailing barrier) -- r18's bug was prefetching into buf1 while COMPUTE(7)
//   read it. Final step uses vmcnt(0) (no prefetch behind it).
//   Value-only DPP min epilogue; per (row, 64-code entry): top-1 value + W-mask.
// finrescue (frozen): merge 16 entries by (value, entry); flag margin<TAU or popcount>1;
//   flagged rows -> bit-exact numpy rescore of candidate codes (validated r3-r17).
// gather (frozen): codebook rows into both outputs.

#define NROWS 65536
#define DDIM 256
#define KCODES 1024
#define TAU 2e-4f
#define WWIN 2e-4f

typedef unsigned long long u64;
typedef _Float16 f16x8 __attribute__((ext_vector_type(8)));
typedef float f32x4 __attribute__((ext_vector_type(4)));

__device__ __forceinline__ void gld16(const void* g, void* l) {
    __builtin_amdgcn_global_load_lds((const __attribute__((address_space(1))) void*)g,
                                     (__attribute__((address_space(3))) void*)l, 16, 0, 0);
}

// numpy pairwise fp32 sum of 256 fl(x_i^2): 128+128 split, 8 accumulators per half,
// fixed combine tree. Bit-matches np.sum(flat*flat, axis=1) (validated r3..r17).
template <typename F>
__device__ __forceinline__ float np_pairwise256_sq(F get) {
    float half[2];
#pragma unroll
    for (int h = 0; h < 2; ++h) {
        float r[8];
#pragma unroll
        for (int j = 0; j < 8; ++j) { float v = get(h * 128 + j); r[j] = __fmul_rn(v, v); }
        for (int i = 8; i < 128; i += 8)
#pragma unroll
            for (int j = 0; j < 8; ++j) {
                float v = get(h * 128 + i + j);
                r[j] = __fadd_rn(r[j], __fmul_rn(v, v));
            }
        half[h] = __fadd_rn(__fadd_rn(__fadd_rn(r[0], r[1]), __fadd_rn(r[2], r[3])),
                            __fadd_rn(__fadd_rn(r[4], r[5]), __fadd_rn(r[6], r[7])));
    }
    return __fadd_rn(half[0], half[1]);
}

// ---------------- prep: w16 = fl16(1024*w) tiled [o][c][8]; wn = np ||w||^2 --------
__global__ void prep_w_k(const float* __restrict__ w, f16x8* __restrict__ w16,
                         float* __restrict__ wn) {
    int bid = blockIdx.x;
    if (bid < 128) {
        int idx = bid * 256 + threadIdx.x;            // 32768 items
        int o = idx >> 10, c = idx & 1023;
        const float* wp = w + (size_t)c * DDIM + o * 8;
        f16x8 hv;
#pragma unroll
        for (int j = 0; j < 8; ++j) hv[j] = (_Float16)(wp[j] * 1024.0f);  // pow2: exact
        w16[(size_t)o * 1024 + c] = hv;
    } else {
        int k = (bid - 128) * 256 + threadIdx.x;
        const float* wp = w + (size_t)k * DDIM;
        wn[k] = np_pairwise256_sq([&](int i) { return wp[i]; });
    }
}

// DPP min stage (16-lane group): pure VALU.
#define DPP_MIN(CTRL) {                                                                 \
    float ov = __int_as_float(__builtin_amdgcn_mov_dpp(__float_as_int(bv), CTRL, 0xf, 0xf, false)); \
    bv = fminf(bv, ov); }

// A-LDS swizzle (r12-validated write/read pair): byte = row*16 ^ ((row>>2)&7)<<4
__device__ __forceinline__ int aswz(int row) {
    return (row * 16) ^ (((row >> 2) & 7) << 4);
}

// ---------------- fused conversion + fp16-MFMA distance ----------------
// Block: 128 rows x 1024 codes; 4 waves 2x2 per code-block (wm row-half, wn_ code-half).
// LDS: A 64KB (static, built once from fp32 z) + B 2x8KB dbuf.
__launch_bounds__(256, 2)
__global__ void argmin_fused_k(const float* __restrict__ z, const f16x8* __restrict__ w16,
                               const float* __restrict__ wn,
                               float* __restrict__ btv, u64* __restrict__ bmk) {
    __shared__ char arena[81920];               // A 64KB | B 2x8KB
    char* lA = arena;
    char* lB = arena + 65536;
    const int t = threadIdx.x;
    const int lane = t & 63;
    const int l15 = lane & 15, l4 = lane >> 4;
    const int wid = t >> 6;                     // 0..3
    const int wm = wid >> 1, wn_ = wid & 1;
    const int n0 = blockIdx.x * 128;
    const float* zb = z + (size_t)(n0 >> 12) * 1048576 + (n0 & 4095);

    auto STAGE_B = [&](int cb, int s, int buf) {
#pragma unroll
        for (int q = 0; q < 2; ++q) {
            int i = wid * 2 + q;                // chunk 0..7 (1KB each)
            int o = s * 4 + (i >> 1);
            int half = i & 1;
            gld16(w16 + (size_t)(o * 1024 + cb * 128 + half * 64 + lane),
                  lB + buf * 8192 + i * 1024);
        }
    };
    STAGE_B(0, 0, 0);                           // hides under A-build

    // ---- A-build: fp32 z -> f16 records, in-register 4x8 transpose, swizzled write --
    {
        int oc = t >> 5;                        // octet offset within pass (0..7)
        int rq = t & 31;                        // row-quad (rows 4rq..4rq+3)
#pragma unroll
        for (int p = 0; p < 4; ++p) {
            int o = p * 8 + oc;                 // 0..31
            float4 L[8];
#pragma unroll
            for (int j = 0; j < 8; ++j)
                L[j] = *reinterpret_cast<const float4*>(zb + (size_t)(o * 8 + j) * 4096 + rq * 4);
#pragma unroll
            for (int k = 0; k < 4; ++k) {
                f16x8 rec;
#pragma unroll
                for (int j = 0; j < 8; ++j) {
                    const float* lj = reinterpret_cast<const float*>(&L[j]);
                    rec[j] = (_Float16)lj[k];   // RNE, same as all validated rounds
                }
                *reinterpret_cast<f16x8*>(lA + o * 2048 + aswz(rq * 4 + k)) = rec;
            }
        }
    }
    __syncthreads();                            // A ready (B cb0/s0 may still be in flight)

    auto COMPUTE = [&](int s, int buf, f32x4 (&acc)[4][4]) {
        f16x8 a[4], b[4];
        const char* pb = lB + buf * 8192 + l4 * 2048 + (wn_ * 64 + l15) * 16;
#pragma unroll
        for (int nt = 0; nt < 4; ++nt) b[nt] = *reinterpret_cast<const f16x8*>(pb + nt * 256);
        const char* pa = lA + (s * 4 + l4) * 2048;
#pragma unroll
        for (int mt = 0; mt < 4; ++mt)
            a[mt] = *reinterpret_cast<const f16x8*>(pa + aswz(wm * 64 + mt * 16 + l15));
#pragma unroll
        for (int mt = 0; mt < 4; ++mt)
#pragma unroll
            for (int nt = 0; nt < 4; ++nt)
                acc[mt][nt] = __builtin_amdgcn_mfma_f32_16x16x32_f16(a[mt], b[nt], acc[mt][nt], 0, 0, 0);
    };

#pragma unroll 1
    for (int cb = 0; cb < 8; ++cb) {
        f32x4 acc[4][4];
#pragma unroll
        for (int mt = 0; mt < 4; ++mt)
#pragma unroll
            for (int nt = 0; nt < 4; ++nt) acc[mt][nt] = f32x4{0.f, 0.f, 0.f, 0.f};

#pragma unroll
        for (int s = 0; s < 8; ++s) {
            // stage ahead: steps 0..6 stage s+1 into buf (s+1)&1; at s=7 prefetch next
            // cb's step 0 into BUF0 (free: last read at COMPUTE(6), sealed by its
            // trailing barrier). Parity then matches next cb's buf = s&1 rule.
            if (s < 7)       STAGE_B(cb, s + 1, (s + 1) & 1);
            else if (cb < 7) STAGE_B(cb + 1, 0, 0);
            if (s == 7 && cb == 7) { asm volatile("s_waitcnt vmcnt(0)" ::: "memory"); }
            else                   { asm volatile("s_waitcnt vmcnt(2)" ::: "memory"); }
            __builtin_amdgcn_s_barrier();
            COMPUTE(s, s & 1, acc);
            __builtin_amdgcn_s_barrier();                    // reads done before overwrite
        }

        // ---- epilogue: s = wn - 2^-9 m'; entry e = cb*2 + wn_ ----
        const int c0 = cb << 7;
        float wnv[4];
#pragma unroll
        for (int nt = 0; nt < 4; ++nt) wnv[nt] = wn[c0 + wn_ * 64 + nt * 16 + l15];
        const int ebase = ((cb << 1) | wn_) << 16;
#pragma unroll
        for (int mt = 0; mt < 4; ++mt) {
#pragma unroll
            for (int r = 0; r < 4; ++r) {
                // C/D layout: col = lane&15, row = (lane>>4)*4 + r
                float s0 = fmaf(-0.001953125f, acc[mt][0][r], wnv[0]);   // -2^-9 (w x1024)
                float s1 = fmaf(-0.001953125f, acc[mt][1][r], wnv[1]);
                float s2 = fmaf(-0.001953125f, acc[mt][2][r], wnv[2]);
                float s3 = fmaf(-0.001953125f, acc[mt][3][r], wnv[3]);
                float bv = fminf(fminf(s0, s1), fminf(s2, s3));
                DPP_MIN(0xB1)      // quad_perm [1,0,3,2]
                DPP_MIN(0x4E)      // quad_perm [2,3,0,1]
                DPP_MIN(0x141)     // row_half_mirror
                DPP_MIN(0x140)     // row_mirror  -> bv = 16-lane-group min
                float thr = bv + WWIN;
                u64 b0 = __ballot(s0 < thr), b1 = __ballot(s1 < thr);
                u64 b2 = __ballot(s2 < thr), b3 = __ballot(s3 < thr);
                int sh = 16 * l4;
                u64 msk = ((b0 >> sh) & 0xFFFFull)
                        | (((b1 >> sh) & 0xFFFFull) << 16)
                        | (((b2 >> sh) & 0xFFFFull) << 32)
                        | (((b3 >> sh) & 0xFFFFull) << 48);
                if (l15 == 0) {
                    int row = wm * 64 + mt * 16 + l4 * 4 + r;
                    btv[ebase + n0 + row] = bv;
                    bmk[ebase + n0 + row] = msk;
                }
            }
        }
    }
}

// ---------------- finalize+rescue fused (frozen): per 16-row group, 64 threads ------
__global__ void finrescue_k(const float* __restrict__ z, const float* __restrict__ w,
                            const float* __restrict__ s2,
                            const float* __restrict__ btv, const u64* __restrict__ bmk,
                            float* __restrict__ idxf_out) {
    __shared__ float zsh[16][256];              // 16KB panel
    const int lane = threadIdx.x;               // 0..63
    const int n0 = blockIdx.x * 16;
    const int r = lane >> 2;                    // row 0..15
    const int eq = lane & 3;                    // entry quarter
    const int n = n0 + r;

    float bv = 3.4e38f, b2 = 3.4e38f;
    int be = 0;
#pragma unroll
    for (int i = 0; i < 4; ++i) {
        int e = eq * 4 + i;
        float v = btv[(e << 16) + n];
        if (v < bv) { b2 = bv; bv = v; be = e; }    // e ascending: strict < keeps first
        else b2 = fminf(b2, v);
    }
#pragma unroll
    for (int m = 1; m < 4; m <<= 1) {
        float ov = __shfl_xor(bv, m), o2 = __shfl_xor(b2, m);
        int oe = __shfl_xor(be, m);
        if (ov < bv || (ov == bv && oe < be)) { b2 = fminf(bv, o2); bv = ov; be = oe; }
        else b2 = fminf(b2, ov);
    }
    u64 wmask = bmk[((u64)be << 16) + n];
    int bi = be * 64 + (int)(__ffsll((long long)wmask) - 1);
    bool flag = (__popcll(wmask) > 1) || (b2 - bv < TAU);
    if (eq == 0) idxf_out[n] = (float)bi;
    u64 fb = __ballot(flag);
    if ((fb & 0x1111111111111111ull) == 0) return;

    const float* zb = z + (size_t)(n0 >> 12) * 1048576 + (n0 & 4095);
#pragma unroll
    for (int it = 0; it < 16; ++it) {
        int d = it * 16 + (lane >> 2);
        float4 v = *reinterpret_cast<const float4*>(zb + (size_t)d * 4096 + (lane & 3) * 4);
        zsh[(lane & 3) * 4 + 0][d] = v.x;
        zsh[(lane & 3) * 4 + 1][d] = v.y;
        zsh[(lane & 3) * 4 + 2][d] = v.z;
        zsh[(lane & 3) * 4 + 3][d] = v.w;
    }
    __syncthreads();

    for (int r2 = 0; r2 < 16; ++r2) {
        if (!((fb >> (r2 * 4)) & 1)) continue;
        int nn = n0 + r2;
        int hh = (lane >> 3) & 1, jj = lane & 7;
        float v0 = zsh[r2][hh * 128 + jj];
        float accj = __fmul_rn(v0, v0);
#pragma unroll
        for (int i = 1; i < 16; ++i) {
            float v2 = zsh[r2][hh * 128 + i * 8 + jj];
            accj = __fadd_rn(accj, __fmul_rn(v2, v2));
        }
        float a1 = __fadd_rn(accj, __shfl_xor(accj, 1));
        float a2 = __fadd_rn(a1, __shfl_xor(a1, 2));
        float a4 = __fadd_rn(a2, __shfl_xor(a2, 4));
        float s1 = __fadd_rn(a4, __shfl_xor(a4, 8));

        float gv = __shfl(bv, r2 * 4);          // global min of row r2 (from merge phase)

        float zr0 = zsh[r2][lane * 4 + 0], zr1 = zsh[r2][lane * 4 + 1];
        float zr2 = zsh[r2][lane * 4 + 2], zr3 = zsh[r2][lane * 4 + 3];
        float bv2 = 3.4e38f;
        int   bi2 = 0;
        for (int e = 0; e < 16; ++e) {          // ascending codes -> first-index ties
            float tv = btv[(e << 16) + nn];
            if (tv <= gv + TAU) {
                u64 m = bmk[((u64)e << 16) + nn];
                while (m) {
                    int k = __ffsll((long long)m) - 1;
                    m &= m - 1;
                    int c = e * 64 + k;
                    const float* wp = w + (size_t)c * DDIM + lane * 4;
                    double md = 0.0;
                    md = fma((double)zr0, (double)wp[0], md);
                    md = fma((double)zr1, (double)wp[1], md);
                    md = fma((double)zr2, (double)wp[2], md);
                    md = fma((double)zr3, (double)wp[3], md);
#pragma unroll
                    for (int mm = 1; mm < 64; mm <<= 1) md += __shfl_xor(md, mm);
                    float dq = __fadd_rn((float)((double)s1 - 2.0 * md), s2[c]);
                    if (dq < bv2) { bv2 = dq; bi2 = c; }
                }
            }
        }
        if (lane == 0) idxf_out[nn] = (float)bi2;
    }
}

// ---------------- gather quantized = weight[idx] into [b,c,h,w] x2 (frozen) --------
__global__ void gather_k(const float* __restrict__ idxf, const float* __restrict__ w,
                         float* __restrict__ out0, float* __restrict__ out1) {
    int tid = blockIdx.x * 256 + threadIdx.x;
    int n   = tid & 65535;
    int c4  = tid >> 16;
    int code = (int)idxf[n];
    float4 v = *reinterpret_cast<const float4*>(w + (size_t)code * DDIM + c4 * 4);
    size_t off = (size_t)(n >> 12) * 1048576 + (size_t)c4 * 4 * 4096 + (n & 4095);
    out0[off]         = v.x;
    out0[off + 4096]  = v.y;
    out0[off + 8192]  = v.z;
    out0[off + 12288] = v.w;
    out1[off]         = v.x;
    out1[off + 4096]  = v.y;
    out1[off + 8192]  = v.z;
    out1[off + 12288] = v.w;
}

extern "C" void kernel_launch(void* const* d_in, const int* in_sizes, int n_in,
                              void* d_out, int out_size, void* d_ws, size_t ws_size,
                              hipStream_t stream) {
    const float* z = (const float*)d_in[0];
    const float* w = (const float*)d_in[1];
    float* out    = (float*)d_out;
    float* out0   = out;
    float* out1   = out + 16777216;
    float* outidx = out + 33554432;

    // scratch inside d_out's out1 region (consumed before gather_k overwrites):
    char* s1b = (char*)out1;
    f16x8* w16 = (f16x8*)s1b;                               // 512KB
    float* wn  = (float*)(s1b + 1048576);                   // 4KB
    float* btv = (float*)(s1b + 2097152);                   // 4MB  [16][65536]
    u64*   bmk = (u64*)(s1b + 10485760);                    // 8MB  [16][65536]

    prep_w_k<<<132, 256, 0, stream>>>(w, w16, wn);
    argmin_fused_k<<<NROWS / 128, 256, 0, stream>>>(z, w16, wn, btv, bmk);
    finrescue_k<<<NROWS / 16, 64, 0, stream>>>(z, w, wn, btv, bmk, outidx);
    gather_k<<<NROWS * 64 / 256, 256, 0, stream>>>(outidx, w, out0, out1);
}